// Round 1
// baseline (78.458 us; speedup 1.0000x reference)
//
#include <hip/hip_runtime.h>
#include <hip/hip_bf16.h>
#include <stdint.h>

// SelfBallPointQuery: B=16, C=3, N=2048, RADIUS^2=0.04, MAX_SAMPLES=64.
// R18 = R17 packed-fp32 test phase, restructured for occupancy:
//   16 waves x 64 lanes per block (1024 thr), each wave owns a 128-point
//   window. 2 blocks/CU x 16 waves = 32 waves/CU = 8 waves/SIMD (100%
//   occupancy, was 50%) to hide the SMEM-chunk latency the SGPR budget
//   exposes (one t-iter of point data ~96 SGPRs = whole budget, so loads
//   can't pipeline deep; more co-resident waves must cover the waits).
// __launch_bounds__(1024, 8) caps VGPR at 64 (est. usage ~50).
// t-loop fully unrolled (4 iters) for cross-iteration load hoisting.
// Per pair-step math unchanged from R17: 8 pk + 2 cmp + 2 addc / 2 points,
// rounding identical to numpy's (dx*dx+dy*dy)+dz*dz in RN.

#define B_DIM 16
#define N_PTS 2048
#define K_OUT 64
#define R2 0.04f
#define WAVES 16
#define BLOCK_T (WAVES * 64)            // 1024
#define JPW (N_PTS / WAVES)             // 128 points per wave
#define WPW (JPW / 32)                  // 4 mask words per lane
#define ROWPAD 65                       // LDS row stride

typedef float v2f __attribute__((ext_vector_type(2)));

__global__ __launch_bounds__(BLOCK_T, 8) void ball_query_kernel(
    const float* __restrict__ pcs,   // (B, 3, N)
    int* __restrict__ out)           // (B, N, 64) int32
{
    __shared__ int rows[64 * ROWPAD];
    __shared__ int cntS[WAVES][64];
    __shared__ int qfS[WAVES][64];

    const int b    = blockIdx.x >> 5;
    const int qg   = blockIdx.x & 31;
    const int tid  = threadIdx.x;
    const int wave = __builtin_amdgcn_readfirstlane(tid >> 6); // uniform
    const int lane = tid & 63;

    const float* __restrict__ sx = pcs + (size_t)b * 3 * N_PTS;
    const float* __restrict__ sy = sx + N_PTS;
    const float* __restrict__ sz = sy + N_PTS;

    const int qi = qg * 64 + lane;
    // pre-negated query coords, broadcast into both halves of a VGPR pair
    const float nx = -sx[qi], ny = -sy[qi], nz = -sz[qi];
    const v2f nqx = {nx, nx}, nqy = {ny, ny}, nqz = {nz, nz};

    const int jbase = wave * JPW;
    int* const obase = out + (size_t)(b * N_PTS + qg * 64) * K_OUT;

    // ---- dense test phase: 4 words x 32 bits per lane, 2 points/step ----
    unsigned mask[WPW];
    #pragma unroll
    for (int t = 0; t < WPW; ++t) {
        unsigned m = 0;
        #pragma unroll
        for (int k = 30; k >= 0; k -= 2) {    // descending pairs: bits k+1, k
            const int j = jbase + t * 32 + k; // wave-uniform, even (8B align)
            const v2f px = *(const v2f*)(sx + j);   // uniform -> s_load
            const v2f py = *(const v2f*)(sy + j);
            const v2f pz = *(const v2f*)(sz + j);
            v2f dx, dy, dz, xx, yy, zz, s0, d2;
            asm("v_pk_add_f32 %0, %1, %2" : "=v"(dx) : "s"(px), "v"(nqx));
            asm("v_pk_add_f32 %0, %1, %2" : "=v"(dy) : "s"(py), "v"(nqy));
            asm("v_pk_add_f32 %0, %1, %2" : "=v"(dz) : "s"(pz), "v"(nqz));
            asm("v_pk_mul_f32 %0, %1, %1" : "=v"(xx) : "v"(dx));
            asm("v_pk_mul_f32 %0, %1, %1" : "=v"(yy) : "v"(dy));
            asm("v_pk_mul_f32 %0, %1, %1" : "=v"(zz) : "v"(dz));
            asm("v_pk_add_f32 %0, %1, %2" : "=v"(s0) : "v"(xx), "v"(yy));
            asm("v_pk_add_f32 %0, %1, %2" : "=v"(d2) : "v"(s0), "v"(zz));
            // bit k+1 (point j+1) first, then bit k (point j)
            m = m + m + (unsigned)(d2.y < R2);
            m = m + m + (unsigned)(d2.x < R2);
        }
        mask[t] = m;
    }

    // per-lane count + first hit within this wave's window
    int cnt = 0;
    #pragma unroll
    for (int t = 0; t < WPW; ++t) cnt += __builtin_popcount(mask[t]);
    int qf = -1;
    #pragma unroll
    for (int t = 0; t < WPW; ++t) {
        if (qf < 0 && mask[t] != 0u)
            qf = jbase + t * 32 + __builtin_ctz(mask[t]);
    }
    cntS[wave][lane] = cnt;
    qfS[wave][lane]  = qf;
    __syncthreads();

    // prefix over earlier waves' counts for my query; global first hit
    int base = 0, tc = 0, gfirst = 0;
    #pragma unroll
    for (int w = 0; w < WAVES; ++w) {
        const int c = cntS[w][lane];
        const int f = qfS[w][lane];
        if (w < wave) base += c;
        gfirst = (tc == 0 && c > 0) ? f : gfirst;
        tc += c;
    }

    // ---- sparse emit into LDS rows (disjoint slot ranges across waves) ----
    int slot = base;
    for (int t = 0; t < WPW; ++t) {
        unsigned m = mask[t];
        while (m != 0u && slot < K_OUT) {
            const int k = (int)__builtin_ctz(m);
            rows[lane * ROWPAD + slot] = jbase + t * 32 + k;
            m &= m - 1u;
            ++slot;
        }
    }

    // ---- pad: 4 slots per wave cover [0,64); fill gfirst where s >= tc ----
    #pragma unroll
    for (int s0i = 0; s0i < K_OUT / WAVES; ++s0i) {
        const int s = wave * (K_OUT / WAVES) + s0i;
        if (s >= tc) rows[lane * ROWPAD + s] = gfirst;
    }
    __syncthreads();

    // ---- coalesced copy-out: 64 rows x 64 ints ----
    #pragma unroll
    for (int it = 0; it < (64 * K_OUT) / BLOCK_T; ++it) {
        const int idx = it * BLOCK_T + tid;
        const int r = idx >> 6;
        const int c = idx & 63;
        obase[idx] = rows[r * ROWPAD + c];
    }
}

extern "C" void kernel_launch(void* const* d_in, const int* in_sizes, int n_in,
                              void* d_out, int out_size, void* d_ws, size_t ws_size,
                              hipStream_t stream) {
    const float* pcs = (const float*)d_in[0];
    int* out = (int*)d_out;
    const int grid = B_DIM * 32;     // 512 blocks
    ball_query_kernel<<<grid, BLOCK_T, 0, stream>>>(pcs, out);
}

// Round 3
// 73.845 us; speedup vs baseline: 1.0625x; 1.0625x over previous
//
#include <hip/hip_runtime.h>
#include <stdint.h>

// SelfBallPointQuery: B=16, C=3, N=2048, RADIUS^2=0.04, MAX_SAMPLES=64.
// R20 = R19 with the writelane builtin (absent on this ROCm) replaced by a
// lane==q guarded assignment (ballot results are wave-uniform SGPRs; q is a
// per-step literal -> v_cmp_eq + exec-masked moves).
// Structure: inverted broadcast. R17/R18 issued 192 narrow SMEM requests/wave
// (3x s_load_dwordx2 per pair-step + lgkmcnt(0) drain each step) -- a shared
// scalar-path serialization that 2x occupancy (R18) provably did not hide.
// Here points live in VGPRs (2/lane, packed v2f, loaded once, coalesced);
// queries broadcast from SGPRs via 24x wide uniform loads (s_load_dwordx8),
// hoistable and compiler-scheduled. Per query-step:
//   8 VOP3P pk ops -> d2 pair, 2 v_cmp (the __ballot) -> 64-bit masks with
//   bit i == point (jbase + set*64 + i), then deposit into lane q's words.
// After 64 steps lane q holds mask[4] for its window -- emit/prefix/pad/
// copy-out phases byte-identical to the verified R18.
// FP exactness: d = (-q) + p (sign-bit flip exact, == p - q), per-component
// squares, (x^2+y^2)+z^2 -- identical rounding to the passing R17.

#define B_DIM 16
#define N_PTS 2048
#define K_OUT 64
#define R2 0.04f
#define WAVES 16
#define BLOCK_T (WAVES * 64)            // 1024
#define JPW (N_PTS / WAVES)             // 128 points per wave
#define WPW (JPW / 32)                  // 4 mask words per lane
#define ROWPAD 65                       // LDS row stride

typedef float v2f __attribute__((ext_vector_type(2)));
typedef float f32x8 __attribute__((ext_vector_type(8)));

__global__ __launch_bounds__(BLOCK_T, 8) void ball_query_kernel(
    const float* __restrict__ pcs,   // (B, 3, N)
    int* __restrict__ out)           // (B, N, 64) int32
{
    __shared__ int rows[64 * ROWPAD];
    __shared__ int cntS[WAVES][64];
    __shared__ int qfS[WAVES][64];

    const int b    = blockIdx.x >> 5;
    const int qg   = blockIdx.x & 31;
    const int tid  = threadIdx.x;
    const int wave = __builtin_amdgcn_readfirstlane(tid >> 6); // uniform
    const int lane = tid & 63;

    const float* __restrict__ sx = pcs + (size_t)b * 3 * N_PTS;
    const float* __restrict__ sy = sx + N_PTS;
    const float* __restrict__ sz = sy + N_PTS;

    const int jbase = wave * JPW;
    const int qb    = qg * 64;
    int* const obase = out + (size_t)(b * N_PTS + qb) * K_OUT;

    // ---- wave-resident points: set0 = jbase+lane, set1 = jbase+64+lane ----
    v2f px, py, pz;
    px.x = sx[jbase + lane]; px.y = sx[jbase + 64 + lane];
    py.x = sy[jbase + lane]; py.y = sy[jbase + 64 + lane];
    pz.x = sz[jbase + lane]; pz.y = sz[jbase + 64 + lane];

    // per-lane mask words (lane = query), filled by guarded deposit
    unsigned w0 = 0, w1 = 0, w2 = 0, w3 = 0;

    #pragma unroll
    for (int c = 0; c < 8; ++c) {
        // 8 queries' coords per chunk, uniform address -> wide scalar loads
        const f32x8 qxv = *(const f32x8*)(sx + qb + c * 8);
        const f32x8 qyv = *(const f32x8*)(sy + qb + c * 8);
        const f32x8 qzv = *(const f32x8*)(sz + qb + c * 8);
        #pragma unroll
        for (int s = 0; s < 8; ++s) {
            const int q = c * 8 + s;
            // negate via sign-bit flip (exact)
            const unsigned bx = __float_as_uint(qxv[s]) ^ 0x80000000u;
            const unsigned by = __float_as_uint(qyv[s]) ^ 0x80000000u;
            const unsigned bz = __float_as_uint(qzv[s]) ^ 0x80000000u;
            v2f nX, nY, nZ;
            nX.x = nX.y = __uint_as_float(bx);
            nY.x = nY.y = __uint_as_float(by);
            nZ.x = nZ.y = __uint_as_float(bz);
            v2f dx, dy, dz, xx, yy, zz, s0, d2;
            asm("v_pk_add_f32 %0, %1, %2" : "=v"(dx) : "s"(nX), "v"(px));
            asm("v_pk_add_f32 %0, %1, %2" : "=v"(dy) : "s"(nY), "v"(py));
            asm("v_pk_add_f32 %0, %1, %2" : "=v"(dz) : "s"(nZ), "v"(pz));
            asm("v_pk_mul_f32 %0, %1, %1" : "=v"(xx) : "v"(dx));
            asm("v_pk_mul_f32 %0, %1, %1" : "=v"(yy) : "v"(dy));
            asm("v_pk_mul_f32 %0, %1, %1" : "=v"(zz) : "v"(dz));
            asm("v_pk_add_f32 %0, %1, %2" : "=v"(s0) : "v"(xx), "v"(yy));
            asm("v_pk_add_f32 %0, %1, %2" : "=v"(d2) : "v"(s0), "v"(zz));
            // wave-uniform hit masks: bit i == point jbase + (set*64) + i
            const unsigned long long b0 = __ballot(d2.x < R2);
            const unsigned long long b1 = __ballot(d2.y < R2);
            // deposit query q's 4 mask words into lane q (uniform sources)
            if (lane == q) {
                w0 = (unsigned)b0;
                w1 = (unsigned)(b0 >> 32);
                w2 = (unsigned)b1;
                w3 = (unsigned)(b1 >> 32);
            }
        }
    }

    unsigned mask[WPW] = { w0, w1, w2, w3 };

    // per-lane count + first hit within this wave's window
    int cnt = 0;
    #pragma unroll
    for (int t = 0; t < WPW; ++t) cnt += __builtin_popcount(mask[t]);
    int qf = -1;
    #pragma unroll
    for (int t = 0; t < WPW; ++t) {
        if (qf < 0 && mask[t] != 0u)
            qf = jbase + t * 32 + __builtin_ctz(mask[t]);
    }
    cntS[wave][lane] = cnt;
    qfS[wave][lane]  = qf;
    __syncthreads();

    // prefix over earlier waves' counts for my query; global first hit
    int base = 0, tc = 0, gfirst = 0;
    #pragma unroll
    for (int w = 0; w < WAVES; ++w) {
        const int c = cntS[w][lane];
        const int f = qfS[w][lane];
        if (w < wave) base += c;
        gfirst = (tc == 0 && c > 0) ? f : gfirst;
        tc += c;
    }

    // ---- sparse emit into LDS rows (disjoint slot ranges across waves) ----
    int slot = base;
    for (int t = 0; t < WPW; ++t) {
        unsigned m = mask[t];
        while (m != 0u && slot < K_OUT) {
            const int k = (int)__builtin_ctz(m);
            rows[lane * ROWPAD + slot] = jbase + t * 32 + k;
            m &= m - 1u;
            ++slot;
        }
    }

    // ---- pad: 4 slots per wave cover [0,64); fill gfirst where s >= tc ----
    #pragma unroll
    for (int s0i = 0; s0i < K_OUT / WAVES; ++s0i) {
        const int s = wave * (K_OUT / WAVES) + s0i;
        if (s >= tc) rows[lane * ROWPAD + s] = gfirst;
    }
    __syncthreads();

    // ---- coalesced copy-out: 64 rows x 64 ints ----
    #pragma unroll
    for (int it = 0; it < (64 * K_OUT) / BLOCK_T; ++it) {
        const int idx = it * BLOCK_T + tid;
        const int r = idx >> 6;
        const int c = idx & 63;
        obase[idx] = rows[r * ROWPAD + c];
    }
}

extern "C" void kernel_launch(void* const* d_in, const int* in_sizes, int n_in,
                              void* d_out, int out_size, void* d_ws, size_t ws_size,
                              hipStream_t stream) {
    const float* pcs = (const float*)d_in[0];
    int* out = (int*)d_out;
    const int grid = B_DIM * 32;     // 512 blocks
    ball_query_kernel<<<grid, BLOCK_T, 0, stream>>>(pcs, out);
}